// Round 3
// baseline (80.774 us; speedup 1.0000x reference)
//
#include <hip/hip_runtime.h>
#include <math.h>

// Problem constants (from reference)
#define B_SZ 8192
#define L_SZ 50
#define D_SZ 128
#define C_SZ 256
#define R_SZ 7

// ---------------------------------------------------------------------------
// Kernel 0: transpose W_cpr [C][2D] -> Wt [2D][C]  (k-major for coalesced GEMM)
// 256 blocks (one per row c), 256 threads (one per k). Tiny (256 KB).
// ---------------------------------------------------------------------------
__global__ __launch_bounds__(256) void k_transpose(const float* __restrict__ W,
                                                   float* __restrict__ Wt) {
    int c = blockIdx.x;
    int k = threadIdx.x;
    Wt[k * C_SZ + c] = W[c * (2 * D_SZ) + k];
}

// ---------------------------------------------------------------------------
// Kernel 1: masked embedding-bag sums.
// One 64-lane wave per batch row; lane owns float2 of the D=128 dim.
// Left and right bags processed as two interleaved load streams (MLP=2).
// Active tokens selected via ballot; masked tokens are skipped entirely
// (mask in {0,1} so skip == multiply-by-mask).
// Output: X[b][0:128] = left_sum, X[b][128:256] = right_sum  (f32, in ws)
// ---------------------------------------------------------------------------
__global__ __launch_bounds__(256) void k_bagsum(const int* __restrict__ ltok,
                                                const int* __restrict__ rtok,
                                                const int* __restrict__ lmask,
                                                const int* __restrict__ rmask,
                                                const float* __restrict__ emb,
                                                float* __restrict__ X) {
    const int wave = threadIdx.x >> 6;
    const int lane = threadIdx.x & 63;
    const int b = blockIdx.x * 4 + wave;

    // Preload this row's tokens+masks into lanes 0..49, broadcast later.
    int lt = 0, rt = 0, lm = 0, rm = 0;
    if (lane < L_SZ) {
        lt = ltok[b * L_SZ + lane];
        lm = lmask[b * L_SZ + lane];
        rt = rtok[b * L_SZ + lane];
        rm = rmask[b * L_SZ + lane];
    }
    unsigned long long balL = __ballot(lm != 0);
    unsigned long long balR = __ballot(rm != 0);

    const float2* emb2 = (const float2*)emb;  // [V][64] of float2
    float2 accL = make_float2(0.f, 0.f);
    float2 accR = make_float2(0.f, 0.f);

    while (balL | balR) {
        float2 eL, eR;
        const bool hL = (balL != 0);
        const bool hR = (balR != 0);
        // Issue both loads before consuming either (2 loads in flight).
        if (hL) {
            int l = __ffsll(balL) - 1;
            balL &= balL - 1;
            int t = __shfl(lt, l);
            eL = emb2[(size_t)t * 64 + lane];
        }
        if (hR) {
            int l = __ffsll(balR) - 1;
            balR &= balR - 1;
            int t = __shfl(rt, l);
            eR = emb2[(size_t)t * 64 + lane];
        }
        if (hL) { accL.x += eL.x; accL.y += eL.y; }
        if (hR) { accR.x += eR.x; accR.y += eR.y; }
    }

    float2* Xo = (float2*)(X + (size_t)b * (2 * D_SZ));
    Xo[lane] = accL;       // dims [0,128)
    Xo[64 + lane] = accR;  // dims [128,256)
}

// ---------------------------------------------------------------------------
// Kernel 2: h = LeakyReLU(X @ W_cpr^T + b_cpr); logits = h @ W_sm^T + b_sm;
//           out = log_softmax(logits).
// Block: 16 batch rows x all 256 cols. 256 threads as 4(row-grp) x 64(col-grp),
// each thread computes a 4x4 register tile. W read from pre-transposed Wt
// (coalesced, L2-resident); X reads are wave-uniform broadcasts. No LDS in
// the K-loop. Epilogue fuses bias+LeakyReLU, the 7-wide head, and log-softmax
// through a small LDS tile.
// ---------------------------------------------------------------------------
__global__ __launch_bounds__(256) void k_mlp(const float* __restrict__ X,
                                             const float* __restrict__ Wt,
                                             const float* __restrict__ b_cpr,
                                             const float* __restrict__ W_sm,
                                             const float* __restrict__ b_sm,
                                             float* __restrict__ out) {
    __shared__ float h_lds[16][260];  // padded row stride
    __shared__ float l_lds[16][8];

    const int tid = threadIdx.x;
    const int row0 = blockIdx.x * 16;
    const int c0 = (tid & 63) * 4;   // 4 output cols per thread
    const int bl0 = (tid >> 6) * 4;  // 4 rows per thread

    float acc[4][4] = {{0.f}};
    const float* Xb = X + (size_t)row0 * C_SZ;

    for (int k = 0; k < C_SZ; k += 4) {
        float4 w0 = *(const float4*)&Wt[(k + 0) * C_SZ + c0];
        float4 w1 = *(const float4*)&Wt[(k + 1) * C_SZ + c0];
        float4 w2 = *(const float4*)&Wt[(k + 2) * C_SZ + c0];
        float4 w3 = *(const float4*)&Wt[(k + 3) * C_SZ + c0];
        float ws[4][4] = {{w0.x, w0.y, w0.z, w0.w},
                          {w1.x, w1.y, w1.z, w1.w},
                          {w2.x, w2.y, w2.z, w2.w},
                          {w3.x, w3.y, w3.z, w3.w}};
#pragma unroll
        for (int i = 0; i < 4; ++i) {
            float4 xv = *(const float4*)&Xb[(bl0 + i) * C_SZ + k];
            float xs[4] = {xv.x, xv.y, xv.z, xv.w};
#pragma unroll
            for (int kk = 0; kk < 4; ++kk) {
#pragma unroll
                for (int j = 0; j < 4; ++j) {
                    acc[i][j] = fmaf(xs[kk], ws[kk][j], acc[i][j]);
                }
            }
        }
    }

    // bias + LeakyReLU -> LDS
#pragma unroll
    for (int i = 0; i < 4; ++i) {
#pragma unroll
        for (int j = 0; j < 4; ++j) {
            float h = acc[i][j] + b_cpr[c0 + j];
            h = (h >= 0.f) ? h : 0.01f * h;
            h_lds[bl0 + i][c0 + j] = h;
        }
    }
    __syncthreads();

    // head: logits[bl][r] = dot(h[bl,:], W_sm[r,:]) + b_sm[r]
    if (tid < 16 * R_SZ) {
        const int bl = tid / R_SZ;
        const int r = tid % R_SZ;
        const float* wr = W_sm + r * C_SZ;
        float s = b_sm[r];
#pragma unroll 4
        for (int c = 0; c < C_SZ; c += 4) {
            s = fmaf(h_lds[bl][c + 0], wr[c + 0], s);
            s = fmaf(h_lds[bl][c + 1], wr[c + 1], s);
            s = fmaf(h_lds[bl][c + 2], wr[c + 2], s);
            s = fmaf(h_lds[bl][c + 3], wr[c + 3], s);
        }
        l_lds[bl][r] = s;
    }
    __syncthreads();

    // log_softmax over R=7, one thread per row
    if (tid < 16) {
        float m = -INFINITY;
#pragma unroll
        for (int r = 0; r < R_SZ; ++r) m = fmaxf(m, l_lds[tid][r]);
        float se = 0.f;
#pragma unroll
        for (int r = 0; r < R_SZ; ++r) se += expf(l_lds[tid][r] - m);
        const float lse = m + logf(se);
        const size_t ob = (size_t)(row0 + tid) * R_SZ;
#pragma unroll
        for (int r = 0; r < R_SZ; ++r) out[ob + r] = l_lds[tid][r] - lse;
    }
}

// ---------------------------------------------------------------------------
extern "C" void kernel_launch(void* const* d_in, const int* in_sizes, int n_in,
                              void* d_out, int out_size, void* d_ws, size_t ws_size,
                              hipStream_t stream) {
    const int* ltok = (const int*)d_in[0];
    const int* rtok = (const int*)d_in[1];
    const int* lmask = (const int*)d_in[2];
    const int* rmask = (const int*)d_in[3];
    const float* emb = (const float*)d_in[4];
    const float* W_cpr = (const float*)d_in[5];
    const float* b_cpr = (const float*)d_in[6];
    const float* W_sm = (const float*)d_in[7];
    const float* b_sm = (const float*)d_in[8];
    float* out = (float*)d_out;

    // workspace layout: X [B][256] f32 (8 MB), then Wt [256][256] f32 (256 KB)
    float* X = (float*)d_ws;
    float* Wt = X + (size_t)B_SZ * 2 * D_SZ;

    k_transpose<<<C_SZ, 2 * D_SZ, 0, stream>>>(W_cpr, Wt);
    k_bagsum<<<B_SZ / 4, 256, 0, stream>>>(ltok, rtok, lmask, rmask, emb, X);
    k_mlp<<<B_SZ / 16, 256, 0, stream>>>(X, Wt, b_cpr, W_sm, b_sm, out);
}

// Round 4
// 78.346 us; speedup vs baseline: 1.0310x; 1.0310x over previous
//
#include <hip/hip_runtime.h>
#include <math.h>

// Problem constants (from reference)
#define B_SZ 8192
#define L_SZ 50
#define D_SZ 128
#define C_SZ 256        // output cols of W_cpr
#define K_SZ 256        // = 2*D, GEMM K
#define R_SZ 7
#define BR   8          // batch rows per block

// ---------------------------------------------------------------------------
// Kernel 0: transpose W_cpr [C][K] -> Wt [K][C], LDS-tiled (both sides
// coalesced). 64 blocks x 256 threads; 256 KB total, ~2 us.
// ---------------------------------------------------------------------------
__global__ __launch_bounds__(256) void k_transpose(const float* __restrict__ W,
                                                   float* __restrict__ Wt) {
    __shared__ float t[32][33];
    const int tx = threadIdx.x & 31;
    const int ty = threadIdx.x >> 5;  // 0..7
    const int k0 = blockIdx.x * 32;
    const int c0 = blockIdx.y * 32;
#pragma unroll
    for (int i = 0; i < 32; i += 8)
        t[ty + i][tx] = W[(size_t)(c0 + ty + i) * K_SZ + k0 + tx];
    __syncthreads();
#pragma unroll
    for (int i = 0; i < 32; i += 8)
        Wt[(size_t)(k0 + ty + i) * C_SZ + c0 + tx] = t[tx][ty + i];
}

// ---------------------------------------------------------------------------
// Fused kernel: masked embedding-bag sums (to LDS) + GEMM + LeakyReLU +
// 7-wide head + log-softmax.
//
// Gather: wave w owns rows {2w, 2w+1}; 4 streams (2 rows x 2 sides). Each
// load instruction fetches TWO tokens of a stream (lanes 0-31 token A as
// float4, lanes 32-63 token B), i.e. 1 KB in flight per instr, 4 KB per
// wave per iteration. Cross-half __shfl_xor(32) reduce at the end.
//
// GEMM: 8 rows x 256 cols per block, 256 threads, acc[2][4] per thread.
// W from pre-transposed Wt (coalesced, L2-resident); X broadcast from LDS.
// ---------------------------------------------------------------------------
__global__ __launch_bounds__(256) void k_fused(
    const int* __restrict__ ltok, const int* __restrict__ rtok,
    const int* __restrict__ lmask, const int* __restrict__ rmask,
    const float* __restrict__ emb, const float* __restrict__ Wt,
    const float* __restrict__ b_cpr, const float* __restrict__ W_sm,
    const float* __restrict__ b_sm, float* __restrict__ out) {

    __shared__ float X_lds[BR][K_SZ];        // 8 KB
    __shared__ float h_lds[BR][C_SZ + 4];    // 8.3 KB, padded, 16B-aligned rows
    __shared__ float part[BR][R_SZ][4];
    __shared__ float l_lds[BR][R_SZ];

    const int tid = threadIdx.x;
    const int wave = tid >> 6;
    const int lane = tid & 63;
    const int hlane = lane & 31;
    const int row0 = blockIdx.x * BR;

    // ---------------- gather phase ----------------
    const int r0 = row0 + wave * 2;
    int lt0 = 0, lm0 = 0, rt0 = 0, rm0 = 0;
    int lt1 = 0, lm1 = 0, rt1 = 0, rm1 = 0;
    if (lane < L_SZ) {
        const size_t o0 = (size_t)r0 * L_SZ + lane;
        const size_t o1 = o0 + L_SZ;
        lt0 = ltok[o0]; lm0 = lmask[o0]; rt0 = rtok[o0]; rm0 = rmask[o0];
        lt1 = ltok[o1]; lm1 = lmask[o1]; rt1 = rtok[o1]; rm1 = rmask[o1];
    }
    unsigned long long bL0 = __ballot(lm0 != 0), bR0 = __ballot(rm0 != 0);
    unsigned long long bL1 = __ballot(lm1 != 0), bR1 = __ballot(rm1 != 0);

    const float4* emb4 = (const float4*)emb;  // [V][32] float4
    float4 aL0 = {0, 0, 0, 0}, aR0 = {0, 0, 0, 0};
    float4 aL1 = {0, 0, 0, 0}, aR1 = {0, 0, 0, 0};

    // pop up to 2 tokens per stream per iteration; lanes<32 take token A,
    // lanes>=32 take token B (scaled by 0 when the stream has only one).
#define POP2(bal, tok, e, sc, hv)                                   \
    {                                                               \
        hv = (bal != 0);                                            \
        if (hv) {                                                   \
            int i1 = __ffsll(bal) - 1; bal &= bal - 1;              \
            bool has2 = (bal != 0);                                 \
            int i2 = has2 ? (__ffsll(bal) - 1) : i1;                \
            if (has2) bal &= bal - 1;                               \
            int tA = __shfl(tok, i1);                               \
            int tB = __shfl(tok, i2);                               \
            int ts = (lane < 32) ? tA : tB;                         \
            e = emb4[(size_t)ts * 32 + hlane];                      \
            sc = (lane < 32 || has2) ? 1.f : 0.f;                   \
        }                                                           \
    }

    while (bL0 | bR0 | bL1 | bR1) {
        float4 e0, e1, e2, e3;
        float s0, s1, s2, s3;
        bool h0, h1, h2, h3;
        POP2(bL0, lt0, e0, s0, h0)
        POP2(bR0, rt0, e1, s1, h1)
        POP2(bL1, lt1, e2, s2, h2)
        POP2(bR1, rt1, e3, s3, h3)
        if (h0) { aL0.x = fmaf(s0, e0.x, aL0.x); aL0.y = fmaf(s0, e0.y, aL0.y);
                  aL0.z = fmaf(s0, e0.z, aL0.z); aL0.w = fmaf(s0, e0.w, aL0.w); }
        if (h1) { aR0.x = fmaf(s1, e1.x, aR0.x); aR0.y = fmaf(s1, e1.y, aR0.y);
                  aR0.z = fmaf(s1, e1.z, aR0.z); aR0.w = fmaf(s1, e1.w, aR0.w); }
        if (h2) { aL1.x = fmaf(s2, e2.x, aL1.x); aL1.y = fmaf(s2, e2.y, aL1.y);
                  aL1.z = fmaf(s2, e2.z, aL1.z); aL1.w = fmaf(s2, e2.w, aL1.w); }
        if (h3) { aR1.x = fmaf(s3, e3.x, aR1.x); aR1.y = fmaf(s3, e3.y, aR1.y);
                  aR1.z = fmaf(s3, e3.z, aR1.z); aR1.w = fmaf(s3, e3.w, aR1.w); }
    }
#undef POP2

    // cross-half reduce: both halves end with the full token sum
#define XHALF(a)                          \
    a.x += __shfl_xor(a.x, 32);           \
    a.y += __shfl_xor(a.y, 32);           \
    a.z += __shfl_xor(a.z, 32);           \
    a.w += __shfl_xor(a.w, 32);
    XHALF(aL0) XHALF(aR0) XHALF(aL1) XHALF(aR1)
#undef XHALF

    // X row layout: floats [0,128) = left sum, [128,256) = right sum.
    // lane k writes float4 index k: lanes 0-31 left dims, 32-63 right dims.
    {
        float4* x0 = (float4*)&X_lds[wave * 2][0];
        x0[lane] = (lane < 32) ? aL0 : aR0;
        float4* x1 = (float4*)&X_lds[wave * 2 + 1][0];
        x1[lane] = (lane < 32) ? aL1 : aR1;
    }
    __syncthreads();

    // ---------------- GEMM phase ----------------
    const int cc = (tid & 63) * 4;   // 4 output cols
    const int rr = (tid >> 6) * 2;   // 2 rows
    float acc[2][4] = {{0.f}};
#pragma unroll 2
    for (int k = 0; k < K_SZ; k += 4) {
        float4 w0 = *(const float4*)&Wt[(k + 0) * C_SZ + cc];
        float4 w1 = *(const float4*)&Wt[(k + 1) * C_SZ + cc];
        float4 w2 = *(const float4*)&Wt[(k + 2) * C_SZ + cc];
        float4 w3 = *(const float4*)&Wt[(k + 3) * C_SZ + cc];
        float4 x0 = *(const float4*)&X_lds[rr][k];
        float4 x1 = *(const float4*)&X_lds[rr + 1][k];
        float xs0[4] = {x0.x, x0.y, x0.z, x0.w};
        float xs1[4] = {x1.x, x1.y, x1.z, x1.w};
        float ws[4][4] = {{w0.x, w0.y, w0.z, w0.w}, {w1.x, w1.y, w1.z, w1.w},
                          {w2.x, w2.y, w2.z, w2.w}, {w3.x, w3.y, w3.z, w3.w}};
#pragma unroll
        for (int kk = 0; kk < 4; ++kk) {
#pragma unroll
            for (int j = 0; j < 4; ++j) {
                acc[0][j] = fmaf(xs0[kk], ws[kk][j], acc[0][j]);
                acc[1][j] = fmaf(xs1[kk], ws[kk][j], acc[1][j]);
            }
        }
    }

    // bias + LeakyReLU -> LDS
#pragma unroll
    for (int i = 0; i < 2; ++i) {
#pragma unroll
        for (int j = 0; j < 4; ++j) {
            float h = acc[i][j] + b_cpr[cc + j];
            h_lds[rr + i][cc + j] = (h >= 0.f) ? h : 0.01f * h;
        }
    }
    __syncthreads();

    // ---------------- head: K-split partial dots ----------------
    if (tid < BR * R_SZ * 4) {           // 224 threads: (bl, r, chunk)
        const int chunk = tid & 3;
        const int r = (tid >> 2) % R_SZ;
        const int bl = tid / (R_SZ * 4);
        const float* wr = W_sm + r * C_SZ;
        const int c0 = chunk * 64;
        float s = 0.f;
#pragma unroll
        for (int c = 0; c < 64; c += 4) {
            float4 hv = *(const float4*)&h_lds[bl][c0 + c];
            s = fmaf(hv.x, wr[c0 + c + 0], s);
            s = fmaf(hv.y, wr[c0 + c + 1], s);
            s = fmaf(hv.z, wr[c0 + c + 2], s);
            s = fmaf(hv.w, wr[c0 + c + 3], s);
        }
        part[bl][r][chunk] = s;
    }
    __syncthreads();

    if (tid < BR * R_SZ) {               // 56 threads: combine + bias
        const int bl = tid / R_SZ;
        const int r = tid % R_SZ;
        l_lds[bl][r] = part[bl][r][0] + part[bl][r][1] +
                       part[bl][r][2] + part[bl][r][3] + b_sm[r];
    }
    __syncthreads();

    // ---------------- log-softmax over R=7 ----------------
    if (tid < BR) {
        float m = -INFINITY;
#pragma unroll
        for (int r = 0; r < R_SZ; ++r) m = fmaxf(m, l_lds[tid][r]);
        float se = 0.f;
#pragma unroll
        for (int r = 0; r < R_SZ; ++r) se += expf(l_lds[tid][r] - m);
        const float lse = m + logf(se);
        const size_t ob = (size_t)(row0 + tid) * R_SZ;
#pragma unroll
        for (int r = 0; r < R_SZ; ++r) out[ob + r] = l_lds[tid][r] - lse;
    }
}

// ---------------------------------------------------------------------------
extern "C" void kernel_launch(void* const* d_in, const int* in_sizes, int n_in,
                              void* d_out, int out_size, void* d_ws, size_t ws_size,
                              hipStream_t stream) {
    const int* ltok = (const int*)d_in[0];
    const int* rtok = (const int*)d_in[1];
    const int* lmask = (const int*)d_in[2];
    const int* rmask = (const int*)d_in[3];
    const float* emb = (const float*)d_in[4];
    const float* W_cpr = (const float*)d_in[5];
    const float* b_cpr = (const float*)d_in[6];
    const float* W_sm = (const float*)d_in[7];
    const float* b_sm = (const float*)d_in[8];
    float* out = (float*)d_out;

    float* Wt = (float*)d_ws;  // [K_SZ][C_SZ] = 256 KB

    k_transpose<<<dim3(K_SZ / 32, C_SZ / 32), 256, 0, stream>>>(W_cpr, Wt);
    k_fused<<<B_SZ / BR, 256, 0, stream>>>(ltok, rtok, lmask, rmask, emb, Wt,
                                           b_cpr, W_sm, b_sm, out);
}